// Round 3
// baseline (226.976 us; speedup 1.0000x reference)
//
#include <hip/hip_runtime.h>

// AtlasAttention v4 — barrier-minimal fused pipeline.
//   gemm1_poly : q = Xb@Wqb^T, 2-phase pipelined staging, swapped-operand MFMA,
//                poly epilogue via LDS bounce -> coalesced P[98304][192] bf16 stores.
//   gemm23     : per 64-row block: P panel staged once in LDS; W1/W2 fragments read
//                directly from global (L2-hot, block-invariant) -> 9 barriers/block.
//
// ws layout (bytes):
//   Xb   @ 0          : 8192*768 bf16   = 12,582,912
//   Wqb  @ 12,582,912 : 768*768  bf16^T = 1,179,648   (Wqb[n][k])
//   W1b  @ 13,762,560 : 512*256  bf16^T = 262,144     (W1b[n][k])
//   W2b  @ 14,024,704 : 64*512   bf16^T = 65,536      (W2b[m][k])
//   b1e  @ 14,090,240 : 512 f32         = 2,048
//   P    @ 14,092,288 : 98304*192 bf16  = 37,748,736  -> ends 51,841,024 (ws >= 114MB)

typedef unsigned short u16;
typedef __attribute__((ext_vector_type(8))) short short8;
typedef __attribute__((ext_vector_type(4))) float f32x4;
typedef __attribute__((ext_vector_type(4))) u16 u16x4;

__device__ __forceinline__ u16 f2bf(float f) {
    unsigned u = __builtin_bit_cast(unsigned, f);
    u += 0x7FFFu + ((u >> 16) & 1u);   // RNE
    return (u16)(u >> 16);
}

__device__ __forceinline__ unsigned cvtpk_bf16(float lo, float hi) {
    unsigned r;
    asm("v_cvt_pk_bf16_f32 %0, %1, %2" : "=v"(r) : "v"(lo), "v"(hi));
    return r;
}

__device__ __forceinline__ void gl2lds16(const void* g, void* l) {
    __builtin_amdgcn_global_load_lds(
        (const __attribute__((address_space(1))) unsigned int*)g,
        (__attribute__((address_space(3))) unsigned int*)l, 16, 0, 0);
}

// ---------------- conversion kernels ----------------

__global__ __launch_bounds__(256) void cast_f32_bf16(const float* __restrict__ in,
                                                     u16* __restrict__ out, int n4) {
    int i = blockIdx.x * 256 + threadIdx.x;
    if (i < n4) {
        float4 v = reinterpret_cast<const float4*>(in)[i];
        u16x4 o = {f2bf(v.x), f2bf(v.y), f2bf(v.z), f2bf(v.w)};
        reinterpret_cast<u16x4*>(out)[i] = o;
    }
}

// in: [R][Cin] fp32; out: [C][R] bf16 (first C cols of in). grid (C/32, R/32), block (32,8).
__global__ __launch_bounds__(256) void transpose_cast(const float* __restrict__ in,
                                                      u16* __restrict__ out,
                                                      int R, int Cin) {
    __shared__ float t[32][33];
    const int c0 = blockIdx.x * 32, r0 = blockIdx.y * 32;
    const int tx = threadIdx.x, ty = threadIdx.y;
    #pragma unroll
    for (int j = 0; j < 32; j += 8)
        t[ty + j][tx] = in[(size_t)(r0 + ty + j) * Cin + c0 + tx];
    __syncthreads();
    #pragma unroll
    for (int j = 0; j < 32; j += 8)
        out[(size_t)(c0 + ty + j) * R + r0 + tx] = f2bf(t[tx][ty + j]);
}

// b1e[n] = b1[n] + c0 * sum_{k<64} W1[k][n].  grid 2 x 256.
__global__ __launch_bounds__(256) void make_b1eff(const float* __restrict__ W1,
                                                  const float* __restrict__ b1,
                                                  const float* __restrict__ coeffs,
                                                  float* __restrict__ b1e) {
    const int n = blockIdx.x * 256 + threadIdx.x;   // 0..511
    float s = 0.f;
    #pragma unroll 8
    for (int k = 0; k < 64; ++k) s += W1[k * 512 + n];
    b1e[n] = b1[n] + coeffs[0] * s;
}

// ---------------- GEMM1 + poly epilogue (v3) ----------------
// Block: 64 tokens x 128 n-cols (2 heads). grid (8192/64=128, 768/128=6) = 768 blocks.
// 4 waves: w0=w&1 -> n-half (64), w1=w>>1 -> token-half (32).
// MFMA operands SWAPPED (Wq-frag first) so lane holds 4 consecutive d per acc reg:
//   D row (quad*4+reg) = n, D col (m16) = token.
// K-loop: 2-phase double-buffered staging, ONE barrier per K-step.
// Epilogue: poly planes -> LDS bounce [128 rows][200 u16] -> coalesced 16B stores.

__global__ __launch_bounds__(256)
void gemm1_poly(const u16* __restrict__ Xb, const u16* __restrict__ Wqb,
                const float* __restrict__ coeffs, u16* __restrict__ P)
{
    __shared__ u16 lds[128 * 200];   // 51.2KB; staging dbuf uses first 24KB

    const int tid = threadIdx.x;
    const int w = tid >> 6, lane = tid & 63;
    const int lrow = lane >> 2, lslot = lane & 3;
    const int m16 = lane & 15, quad = lane >> 4;
    const int w0 = w & 1, w1 = w >> 1;
    const int tok0 = blockIdx.x * 64;
    const int bn = blockIdx.y * 128;
    const int h0 = blockIdx.y * 2;

    const float c1 = coeffs[1], c2 = coeffs[2], c3 = coeffs[3];

    f32x4 acc[4][2];
    #pragma unroll
    for (int i = 0; i < 4; ++i)
        #pragma unroll
        for (int j = 0; j < 2; ++j)
            acc[i][j] = (f32x4){0.f, 0.f, 0.f, 0.f};

    auto stage = [&](int buf, int k0) {
        u16* Xs = lds + buf * 6144;          // [64][32]
        u16* Ws = Xs + 2048;                 // [128][32]
        {
            const int row = w * 16 + lrow;
            const int cc = lslot ^ ((row >> 2) & 3);
            gl2lds16(Xb + (size_t)(tok0 + row) * 768 + k0 + cc * 8, &Xs[row * 32 + lslot * 8]);
        }
        #pragma unroll
        for (int i = 0; i < 2; ++i) {
            const int row = (w * 2 + i) * 16 + lrow;
            const int cc = lslot ^ ((row >> 2) & 3);
            gl2lds16(Wqb + (size_t)(bn + row) * 768 + k0 + cc * 8, &Ws[row * 32 + lslot * 8]);
        }
    };

    stage(0, 0);
    __syncthreads();
    int cur = 0;

    for (int k0 = 0; k0 < 768; k0 += 32) {
        if (k0 + 32 < 768) stage(cur ^ 1, k0 + 32);    // prefetch next tile
        const u16* Xs = lds + cur * 6144;
        const u16* Ws = Xs + 2048;
        short8 a[4], b[2];
        #pragma unroll
        for (int i = 0; i < 4; ++i) {
            const int row = w0 * 64 + i * 16 + m16;    // n local
            const int ss = quad ^ ((row >> 2) & 3);
            a[i] = *reinterpret_cast<const short8*>(&Ws[row * 32 + ss * 8]);
        }
        #pragma unroll
        for (int j = 0; j < 2; ++j) {
            const int row = w1 * 32 + j * 16 + m16;    // token local
            const int ss = quad ^ ((row >> 2) & 3);
            b[j] = *reinterpret_cast<const short8*>(&Xs[row * 32 + ss * 8]);
        }
        #pragma unroll
        for (int i = 0; i < 4; ++i)
            #pragma unroll
            for (int j = 0; j < 2; ++j)
                acc[i][j] = __builtin_amdgcn_mfma_f32_16x16x32_bf16(a[i], b[j], acc[i][j], 0, 0, 0);
        __syncthreads();                               // drains this iter's stage too
        cur ^= 1;
    }

    // ---- poly epilogue: pack 4 consecutive d per lane -> uint2 LDS writes ----
    // LDS row = tokLocal*2 + w0 (= head offset), row stride 200 u16 (400B, 16B aligned)
    #pragma unroll
    for (int i = 0; i < 4; ++i) {
        const int d0 = i * 16 + quad * 4;
        #pragma unroll
        for (int j = 0; j < 2; ++j) {
            const int tokLocal = w1 * 32 + j * 16 + m16;
            u16* base = &lds[(tokLocal * 2 + w0) * 200 + d0];
            float x[4], x2[4];
            #pragma unroll
            for (int r = 0; r < 4; ++r) {
                x[r] = fminf(fmaxf(acc[i][j][r], -10.f), 10.f);
                x2[r] = x[r] * x[r];
            }
            uint2 p1, p2, p3;
            p1.x = cvtpk_bf16(c1 * x[0], c1 * x[1]);
            p1.y = cvtpk_bf16(c1 * x[2], c1 * x[3]);
            p2.x = cvtpk_bf16(c2 * x2[0], c2 * x2[1]);
            p2.y = cvtpk_bf16(c2 * x2[2], c2 * x2[3]);
            p3.x = cvtpk_bf16(c3 * x2[0] * x[0], c3 * x2[1] * x[1]);
            p3.y = cvtpk_bf16(c3 * x2[2] * x[2], c3 * x2[3] * x[3]);
            *reinterpret_cast<uint2*>(base)       = p1;
            *reinterpret_cast<uint2*>(base + 64)  = p2;
            *reinterpret_cast<uint2*>(base + 128) = p3;
        }
    }
    __syncthreads();

    // ---- cooperative coalesced store: 12 x dwordx4 per thread ----
    #pragma unroll
    for (int ii = 0; ii < 12; ++ii) {
        const int flat = ii * 256 + tid;       // 0..3071
        const int rowL = flat / 24, ck = flat % 24;
        const int tokL = rowL >> 1, hh = rowL & 1;
        const size_t prow = ((size_t)(tok0 + tokL) * 12 + h0 + hh);
        short8 v = *reinterpret_cast<const short8*>(&lds[rowL * 200 + ck * 8]);
        *reinterpret_cast<short8*>(P + prow * 192 + ck * 8) = v;
    }
}

// ---------------- fused GEMM2+GEMM3 (v4) ----------------
// Block: 64 flat rows. grid 1536 (= 2.0 even rounds at 3 blocks/CU).
// P panel staged ONCE into LDS (24KB, 6 swizzled chunk planes).
// W1/W2 fragments read directly from global (L2-hot) -> no weight barriers.
// Per slice s (128 mem_hid): accH = W1s @ P^T (GEMM2, no barriers),
//   barA, drain->Hs (16KB), barB, accO += Hs @ W2s^T.  9 barriers/block total.

__global__ __launch_bounds__(256, 3)
void gemm23(const u16* __restrict__ P, const u16* __restrict__ W1t,
            const float* __restrict__ b1e, const u16* __restrict__ W2t,
            const float* __restrict__ b2, float* __restrict__ out)
{
    __shared__ u16 Ps[6][64 * 32];   // 24KB: P panel, 6 k-chunk planes, swizzled
    __shared__ u16 Hs[4][64 * 32];   // 16KB: H slice (token-major, 4 nH chunks)

    const int tid = threadIdx.x;
    const int w = tid >> 6, lane = tid & 63;
    const int lrow = lane >> 2, lslot = lane & 3;
    const int m16 = lane & 15, quad = lane >> 4;
    const size_t r0 = (size_t)blockIdx.x * 64;
    const int w0 = w & 1, w1 = w >> 1;

    // ---- stage P panel once (6 gl2lds per thread) ----
    #pragma unroll
    for (int c = 0; c < 6; ++c) {
        const int row = w * 16 + lrow;
        const int cc = lslot ^ ((row >> 2) & 3);
        gl2lds16(P + (r0 + row) * 192 + c * 32 + cc * 8, &Ps[c][row * 32 + lslot * 8]);
    }

    f32x4 accO[2][2];
    #pragma unroll
    for (int i = 0; i < 2; ++i)
        #pragma unroll
        for (int j = 0; j < 2; ++j)
            accO[i][j] = (f32x4){0.f, 0.f, 0.f, 0.f};

    __syncthreads();   // P panel ready

    #pragma unroll 1
    for (int s = 0; s < 4; ++s) {
        // ---- GEMM2 slice: accH[nH 4x16][tok 2x16], K=192, af global, bf LDS ----
        f32x4 accH[4][2];
        #pragma unroll
        for (int i = 0; i < 4; ++i)
            #pragma unroll
            for (int j = 0; j < 2; ++j)
                accH[i][j] = (f32x4){0.f, 0.f, 0.f, 0.f};

        short8 afn[4];
        #pragma unroll
        for (int i = 0; i < 4; ++i)
            afn[i] = *reinterpret_cast<const short8*>(
                W1t + (size_t)(s * 128 + w0 * 64 + i * 16 + m16) * 256 + 64 + quad * 8);

        #pragma unroll
        for (int c = 0; c < 6; ++c) {
            short8 af[4];
            #pragma unroll
            for (int i = 0; i < 4; ++i) af[i] = afn[i];
            if (c < 5) {
                #pragma unroll
                for (int i = 0; i < 4; ++i)
                    afn[i] = *reinterpret_cast<const short8*>(
                        W1t + (size_t)(s * 128 + w0 * 64 + i * 16 + m16) * 256
                            + 64 + (c + 1) * 32 + quad * 8);
            }
            short8 bf[2];
            #pragma unroll
            for (int j = 0; j < 2; ++j) {
                const int row = w1 * 32 + j * 16 + m16;
                const int ss = quad ^ ((row >> 2) & 3);
                bf[j] = *reinterpret_cast<const short8*>(&Ps[c][row * 32 + ss * 8]);
            }
            #pragma unroll
            for (int i = 0; i < 4; ++i)
                #pragma unroll
                for (int j = 0; j < 2; ++j)
                    accH[i][j] = __builtin_amdgcn_mfma_f32_16x16x32_bf16(af[i], bf[j], accH[i][j], 0, 0, 0);
        }

        __syncthreads();   // barA: prev GEMM3 done reading Hs

        // ---- drain: Hs[token][nH] = bf16(relu(accH + b1e)), 8B k-contiguous writes ----
        #pragma unroll
        for (int i = 0; i < 4; ++i) {
            const int lb = w0 * 64 + i * 16 + quad * 4;     // nH local (4 consecutive)
            const f32x4 bv = *reinterpret_cast<const f32x4*>(&b1e[s * 128 + lb]);
            const int hc = lb >> 5;
            #pragma unroll
            for (int j = 0; j < 2; ++j) {
                const int tc = w1 * 32 + j * 16 + m16;      // token local
                const float h0v = fmaxf(accH[i][j][0] + bv[0], 0.f);
                const float h1v = fmaxf(accH[i][j][1] + bv[1], 0.f);
                const float h2v = fmaxf(accH[i][j][2] + bv[2], 0.f);
                const float h3v = fmaxf(accH[i][j][3] + bv[3], 0.f);
                uint2 v;
                v.x = cvtpk_bf16(h0v, h1v);
                v.y = cvtpk_bf16(h2v, h3v);
                const int sl = ((lb >> 3) & 3) ^ ((tc >> 2) & 3);
                *reinterpret_cast<uint2*>(&Hs[hc][tc * 32 + sl * 8 + (lb & 7)]) = v;
            }
        }

        __syncthreads();   // barB: Hs complete

        // ---- GEMM3 partial: accO += Hs @ W2s^T (b3 direct from global) ----
        #pragma unroll
        for (int c = 0; c < 4; ++c) {
            short8 a3[2], b3[2];
            #pragma unroll
            for (int i = 0; i < 2; ++i) {
                const int tr = w0 * 32 + i * 16 + m16;      // token local
                const int ss = quad ^ ((tr >> 2) & 3);
                a3[i] = *reinterpret_cast<const short8*>(&Hs[c][tr * 32 + ss * 8]);
            }
            #pragma unroll
            for (int j = 0; j < 2; ++j)
                b3[j] = *reinterpret_cast<const short8*>(
                    W2t + (size_t)(w1 * 32 + j * 16 + m16) * 512 + s * 128 + c * 32 + quad * 8);
            #pragma unroll
            for (int i = 0; i < 2; ++i)
                #pragma unroll
                for (int j = 0; j < 2; ++j)
                    accO[i][j] = __builtin_amdgcn_mfma_f32_16x16x32_bf16(a3[i], b3[j], accO[i][j], 0, 0, 0);
        }
        // no barrier: next slice's GEMM2 doesn't touch Hs; barA protects the next drain
    }

    // ---- epilogue: out[r0+row][col] = accO + b2 ----
    #pragma unroll
    for (int j = 0; j < 2; ++j) {
        const int col = w1 * 32 + j * 16 + m16;
        const float bv = b2[col];
        #pragma unroll
        for (int i = 0; i < 2; ++i) {
            #pragma unroll
            for (int r = 0; r < 4; ++r) {
                const int row = w0 * 32 + i * 16 + quad * 4 + r;
                out[(r0 + row) * 64 + col] = accO[i][j][r] + bv;
            }
        }
    }
}

// ---------------- host ----------------

extern "C" void kernel_launch(void* const* d_in, const int* in_sizes, int n_in,
                              void* d_out, int out_size, void* d_ws, size_t ws_size,
                              hipStream_t stream) {
    const float* X      = (const float*)d_in[0];
    const float* Wq     = (const float*)d_in[1];
    const float* coeffs = (const float*)d_in[2];
    const float* W1     = (const float*)d_in[3];
    const float* b1     = (const float*)d_in[4];
    const float* W2     = (const float*)d_in[5];
    const float* b2     = (const float*)d_in[6];

    char* ws = (char*)d_ws;
    u16*   Xb  = (u16*)(ws);
    u16*   Wqb = (u16*)(ws + 12582912);
    u16*   W1b = (u16*)(ws + 13762560);
    u16*   W2b = (u16*)(ws + 14024704);
    float* b1e = (float*)(ws + 14090240);
    u16*   P   = (u16*)(ws + 14092288);

    cast_f32_bf16<<<6144, 256, 0, stream>>>(X, Xb, 8192 * 768 / 4);
    transpose_cast<<<dim3(24, 24), dim3(32, 8), 0, stream>>>(Wq, Wqb, 768, 768);
    transpose_cast<<<dim3(16, 8),  dim3(32, 8), 0, stream>>>(W1, W1b, 256, 512);
    transpose_cast<<<dim3(2, 16),  dim3(32, 8), 0, stream>>>(W2, W2b, 512, 256);
    make_b1eff<<<2, 256, 0, stream>>>(W1, b1, coeffs, b1e);

    // GEMM1 + poly epilogue: P = poly(clip(Xb @ Wqb^T)), K folded 256->192
    gemm1_poly<<<dim3(128, 6), 256, 0, stream>>>(Xb, Wqb, coeffs, P);

    // fused GEMM2+GEMM3: out = relu(P @ W1[64:]^T + b1e) @ W2^T + b2
    gemm23<<<dim3(1536), 256, 0, stream>>>(P, W1b, b1e, W2b, b2, (float*)d_out);
}

// Round 4
// 163.252 us; speedup vs baseline: 1.3903x; 1.3903x over previous
//
#include <hip/hip_runtime.h>

// AtlasAttention v5 — 3-launch pipeline (launch-gap consolidation).
//   prep       : ONE kernel: cast X->bf16, transpose Wq/W1/W2, build b1e.
//   gemm1_poly : q = Xb@Wqb^T, pipelined staging, swapped-operand MFMA,
//                poly epilogue -> coalesced P[98304][192] bf16.
//   gemm23     : (round-2 proven, 58us) per 128-row block: H slice in LDS,
//                out += H @ W2^T, no H round-trip through HBM.
//
// ws layout (bytes):
//   Xb   @ 0          : 8192*768 bf16   = 12,582,912
//   Wqb  @ 12,582,912 : 768*768  bf16^T = 1,179,648   (Wqb[n][k])
//   W1b  @ 13,762,560 : 512*256  bf16^T = 262,144     (W1b[n][k])
//   W2b  @ 14,024,704 : 64*512   bf16^T = 65,536      (W2b[m][k])
//   b1e  @ 14,090,240 : 512 f32         = 2,048
//   P    @ 14,092,288 : 98304*192 bf16  = 37,748,736  -> ends 51,841,024 (ws >= 114MB)

typedef unsigned short u16;
typedef __attribute__((ext_vector_type(8))) short short8;
typedef __attribute__((ext_vector_type(4))) float f32x4;
typedef __attribute__((ext_vector_type(4))) u16 u16x4;

__device__ __forceinline__ u16 f2bf(float f) {
    unsigned u = __builtin_bit_cast(unsigned, f);
    u += 0x7FFFu + ((u >> 16) & 1u);   // RNE
    return (u16)(u >> 16);
}

__device__ __forceinline__ unsigned cvtpk_bf16(float lo, float hi) {
    unsigned r;
    asm("v_cvt_pk_bf16_f32 %0, %1, %2" : "=v"(r) : "v"(lo), "v"(hi));
    return r;
}

__device__ __forceinline__ void gl2lds16(const void* g, void* l) {
    __builtin_amdgcn_global_load_lds(
        (const __attribute__((address_space(1))) unsigned int*)g,
        (__attribute__((address_space(3))) unsigned int*)l, 16, 0, 0);
}

// ---------------- fused prep kernel ----------------
// grid 6882 x 256:
//   blocks [0,6144)      : cast X (float4 -> 4x bf16)
//   blocks [6144,6720)   : transpose Wq  (768x768,  24x24 tiles)
//   blocks [6720,6848)   : transpose W1  (R=256,Cin=512, 16x8 tiles)
//   blocks [6848,6880)   : transpose W2  (R=512,Cin=256, 2x16 tiles)
//   blocks [6880,6882)   : b1e[n] = b1[n] + c0 * sum_{k<64} W1[k][n]

__global__ __launch_bounds__(256)
void prep(const float* __restrict__ X, u16* __restrict__ Xb,
          const float* __restrict__ Wq, u16* __restrict__ Wqb,
          const float* __restrict__ W1, u16* __restrict__ W1b,
          const float* __restrict__ W2, u16* __restrict__ W2b,
          const float* __restrict__ b1, const float* __restrict__ coeffs,
          float* __restrict__ b1e)
{
    __shared__ float t[32][33];
    const int b = blockIdx.x, tid = threadIdx.x;

    if (b < 6144) {                       // ---- cast X ----
        const int i = b * 256 + tid;      // 6144*256 = 1,572,864 = 8192*768/4
        float4 v = reinterpret_cast<const float4*>(X)[i];
        u16x4 o = {f2bf(v.x), f2bf(v.y), f2bf(v.z), f2bf(v.w)};
        reinterpret_cast<u16x4*>(Xb)[i] = o;
    } else if (b < 6880) {                // ---- transposes ----
        const float* in; u16* out; int R, Cin, bx, by;
        int lb = b - 6144;
        if (lb < 576)      { in = Wq; out = Wqb; R = 768; Cin = 768; bx = lb % 24; by = lb / 24; }
        else if (lb < 704) { lb -= 576; in = W1; out = W1b; R = 256; Cin = 512; bx = lb % 16; by = lb / 16; }
        else               { lb -= 704; in = W2; out = W2b; R = 512; Cin = 256; bx = lb % 2;  by = lb / 2; }
        const int c0 = bx * 32, r0 = by * 32;
        const int tx = tid & 31, ty = tid >> 5;
        #pragma unroll
        for (int j = 0; j < 32; j += 8)
            t[ty + j][tx] = in[(size_t)(r0 + ty + j) * Cin + c0 + tx];
        __syncthreads();
        #pragma unroll
        for (int j = 0; j < 32; j += 8)
            out[(size_t)(c0 + ty + j) * R + r0 + tx] = f2bf(t[tx][ty + j]);
    } else {                              // ---- b1e ----
        const int n = (b - 6880) * 256 + tid;   // 0..511
        float s = 0.f;
        #pragma unroll 8
        for (int k = 0; k < 64; ++k) s += W1[k * 512 + n];
        b1e[n] = b1[n] + coeffs[0] * s;
    }
}

// ---------------- GEMM1 + poly epilogue ----------------
// Block: 64 tokens x 128 n-cols (2 heads). grid (128, 6) = 768 blocks.
// MFMA operands swapped (Wq-frag first) so lane holds 4 consecutive d per acc reg.
// K-loop: double-buffered staging, one barrier per K-step.
// Epilogue: poly planes -> LDS bounce [128 rows][200 u16] -> coalesced 16B stores.

__global__ __launch_bounds__(256)
void gemm1_poly(const u16* __restrict__ Xb, const u16* __restrict__ Wqb,
                const float* __restrict__ coeffs, u16* __restrict__ P)
{
    __shared__ u16 lds[128 * 200];   // 51.2KB; staging dbuf uses first 24KB

    const int tid = threadIdx.x;
    const int w = tid >> 6, lane = tid & 63;
    const int lrow = lane >> 2, lslot = lane & 3;
    const int m16 = lane & 15, quad = lane >> 4;
    const int w0 = w & 1, w1 = w >> 1;
    const int tok0 = blockIdx.x * 64;
    const int bn = blockIdx.y * 128;
    const int h0 = blockIdx.y * 2;

    const float c1 = coeffs[1], c2 = coeffs[2], c3 = coeffs[3];

    f32x4 acc[4][2];
    #pragma unroll
    for (int i = 0; i < 4; ++i)
        #pragma unroll
        for (int j = 0; j < 2; ++j)
            acc[i][j] = (f32x4){0.f, 0.f, 0.f, 0.f};

    auto stage = [&](int buf, int k0) {
        u16* Xs = lds + buf * 6144;          // [64][32]
        u16* Ws = Xs + 2048;                 // [128][32]
        {
            const int row = w * 16 + lrow;
            const int cc = lslot ^ ((row >> 2) & 3);
            gl2lds16(Xb + (size_t)(tok0 + row) * 768 + k0 + cc * 8, &Xs[row * 32 + lslot * 8]);
        }
        #pragma unroll
        for (int i = 0; i < 2; ++i) {
            const int row = (w * 2 + i) * 16 + lrow;
            const int cc = lslot ^ ((row >> 2) & 3);
            gl2lds16(Wqb + (size_t)(bn + row) * 768 + k0 + cc * 8, &Ws[row * 32 + lslot * 8]);
        }
    };

    stage(0, 0);
    __syncthreads();
    int cur = 0;

    for (int k0 = 0; k0 < 768; k0 += 32) {
        if (k0 + 32 < 768) stage(cur ^ 1, k0 + 32);    // prefetch next tile
        const u16* Xs = lds + cur * 6144;
        const u16* Ws = Xs + 2048;
        short8 a[4], b[2];
        #pragma unroll
        for (int i = 0; i < 4; ++i) {
            const int row = w0 * 64 + i * 16 + m16;    // n local
            const int ss = quad ^ ((row >> 2) & 3);
            a[i] = *reinterpret_cast<const short8*>(&Ws[row * 32 + ss * 8]);
        }
        #pragma unroll
        for (int j = 0; j < 2; ++j) {
            const int row = w1 * 32 + j * 16 + m16;    // token local
            const int ss = quad ^ ((row >> 2) & 3);
            b[j] = *reinterpret_cast<const short8*>(&Xs[row * 32 + ss * 8]);
        }
        #pragma unroll
        for (int i = 0; i < 4; ++i)
            #pragma unroll
            for (int j = 0; j < 2; ++j)
                acc[i][j] = __builtin_amdgcn_mfma_f32_16x16x32_bf16(a[i], b[j], acc[i][j], 0, 0, 0);
        __syncthreads();                               // drains this iter's stage too
        cur ^= 1;
    }

    // ---- poly epilogue: pack 4 consecutive d per lane -> uint2 LDS writes ----
    #pragma unroll
    for (int i = 0; i < 4; ++i) {
        const int d0 = i * 16 + quad * 4;
        #pragma unroll
        for (int j = 0; j < 2; ++j) {
            const int tokLocal = w1 * 32 + j * 16 + m16;
            u16* base = &lds[(tokLocal * 2 + w0) * 200 + d0];
            float x[4], x2[4];
            #pragma unroll
            for (int r = 0; r < 4; ++r) {
                x[r] = fminf(fmaxf(acc[i][j][r], -10.f), 10.f);
                x2[r] = x[r] * x[r];
            }
            uint2 p1, p2, p3;
            p1.x = cvtpk_bf16(c1 * x[0], c1 * x[1]);
            p1.y = cvtpk_bf16(c1 * x[2], c1 * x[3]);
            p2.x = cvtpk_bf16(c2 * x2[0], c2 * x2[1]);
            p2.y = cvtpk_bf16(c2 * x2[2], c2 * x2[3]);
            p3.x = cvtpk_bf16(c3 * x2[0] * x[0], c3 * x2[1] * x[1]);
            p3.y = cvtpk_bf16(c3 * x2[2] * x[2], c3 * x2[3] * x[3]);
            *reinterpret_cast<uint2*>(base)       = p1;
            *reinterpret_cast<uint2*>(base + 64)  = p2;
            *reinterpret_cast<uint2*>(base + 128) = p3;
        }
    }
    __syncthreads();

    // ---- cooperative coalesced store: 12 x dwordx4 per thread ----
    #pragma unroll
    for (int ii = 0; ii < 12; ++ii) {
        const int flat = ii * 256 + tid;       // 0..3071
        const int rowL = flat / 24, ck = flat % 24;
        const int tokL = rowL >> 1, hh = rowL & 1;
        const size_t prow = ((size_t)(tok0 + tokL) * 12 + h0 + hh);
        short8 v = *reinterpret_cast<const short8*>(&lds[rowL * 200 + ck * 8]);
        *reinterpret_cast<short8*>(P + prow * 192 + ck * 8) = v;
    }
}

// ---------------- fused GEMM2+GEMM3 (round-2 proven, 58us) ----------------
// Per block (256 thr, 4 waves): 128 token-rows. accO held across 4 mem_hid slices:
//   slice s: accH[nH 128][tok 128] = W1slice @ P^T (transposed so drain to LDS is
//   k-contiguous); drain = bf16(relu(accH + b1e)) -> Hs; accO += Hs @ W2slice^T.
__global__ __launch_bounds__(256)
void gemm23(const u16* __restrict__ P, const u16* __restrict__ W1t,
            const float* __restrict__ b1e, const u16* __restrict__ W2t,
            const float* __restrict__ b2, float* __restrict__ out)
{
    __shared__ u16 As[128 * 32];      // GEMM2: W1 chunk (nH-major)   | GEMM3: W2 chunks 0,1
    __shared__ u16 Bs[128 * 32];      // GEMM2: poly chunk (tok-major)| GEMM3: W2 chunks 2,3
    __shared__ u16 Hs[4][128 * 32];   // H slice, token-major, per-32k swizzled slots

    const int tid = threadIdx.x;
    const int w = tid >> 6, lane = tid & 63;
    const int lrow = lane >> 2, lslot = lane & 3;
    const int m16 = lane & 15, quad = lane >> 4;
    const size_t r0 = (size_t)blockIdx.x * 128;
    const int w0 = w & 1, w1 = w >> 1;

    f32x4 accO[4][2];
    #pragma unroll
    for (int i = 0; i < 4; ++i)
        #pragma unroll
        for (int j = 0; j < 2; ++j)
            accO[i][j] = (f32x4){0.f, 0.f, 0.f, 0.f};

    #pragma unroll 1
    for (int s = 0; s < 4; ++s) {
        f32x4 accH[4][4];
        #pragma unroll
        for (int i = 0; i < 4; ++i)
            #pragma unroll
            for (int j = 0; j < 4; ++j)
                accH[i][j] = (f32x4){0.f, 0.f, 0.f, 0.f};

        for (int c = 0; c < 6; ++c) {
            #pragma unroll
            for (int i = 0; i < 2; ++i) {
                const int row = (w * 2 + i) * 16 + lrow;
                const int cc = lslot ^ ((row >> 2) & 3);
                gl2lds16(W1t + (size_t)(s * 128 + row) * 256 + 64 + c * 32 + cc * 8,
                         &As[row * 32 + lslot * 8]);
                gl2lds16(P + (r0 + row) * 192 + c * 32 + cc * 8,
                         &Bs[row * 32 + lslot * 8]);
            }
            __syncthreads();

            short8 af[4], bf[4];
            #pragma unroll
            for (int i = 0; i < 4; ++i) {
                const int row = w0 * 64 + i * 16 + m16;          // nH local
                const int ss = quad ^ ((row >> 2) & 3);
                af[i] = *reinterpret_cast<const short8*>(&As[row * 32 + ss * 8]);
            }
            #pragma unroll
            for (int j = 0; j < 4; ++j) {
                const int row = w1 * 64 + j * 16 + m16;          // token local
                const int ss = quad ^ ((row >> 2) & 3);
                bf[j] = *reinterpret_cast<const short8*>(&Bs[row * 32 + ss * 8]);
            }
            #pragma unroll
            for (int i = 0; i < 4; ++i)
                #pragma unroll
                for (int j = 0; j < 4; ++j)
                    accH[i][j] = __builtin_amdgcn_mfma_f32_16x16x32_bf16(af[i], bf[j], accH[i][j], 0, 0, 0);
            __syncthreads();
        }

        // ---- drain: Hs[token][nH] = bf16(relu(accH + b1e)); k-contiguous b64 writes ----
        #pragma unroll
        for (int i = 0; i < 4; ++i) {
            const int lb = w0 * 64 + i * 16 + quad * 4;          // nH local base (4 consecutive)
            const f32x4 bv = *reinterpret_cast<const f32x4*>(&b1e[s * 128 + lb]);
            const int hc = lb >> 5;                              // Hs chunk (32-wide k group)
            #pragma unroll
            for (int j = 0; j < 4; ++j) {
                const int tc = w1 * 64 + j * 16 + m16;           // token local
                const float h0 = fmaxf(accH[i][j][0] + bv[0], 0.f);
                const float h1 = fmaxf(accH[i][j][1] + bv[1], 0.f);
                const float h2 = fmaxf(accH[i][j][2] + bv[2], 0.f);
                const float h3 = fmaxf(accH[i][j][3] + bv[3], 0.f);
                uint2 v;
                v.x = cvtpk_bf16(h0, h1);
                v.y = cvtpk_bf16(h2, h3);
                const int sl = ((lb >> 3) & 3) ^ ((tc >> 2) & 3);
                *reinterpret_cast<uint2*>(&Hs[hc][tc * 32 + sl * 8 + (lb & 7)]) = v;
            }
        }

        // ---- stage full W2 slice (64 rows x 128 k, 4 chunks) into As/Bs; chunk = wave ----
        {
            u16* dst = (w < 2) ? As : Bs;
            #pragma unroll
            for (int i = 0; i < 4; ++i) {
                const int row = i * 16 + lrow;                   // 0..63 (out col m)
                const int cc = lslot ^ ((row >> 2) & 3);
                gl2lds16(W2t + (size_t)row * 512 + s * 128 + w * 32 + cc * 8,
                         dst + (w & 1) * 2048 + row * 32 + lslot * 8);
            }
        }
        __syncthreads();

        // ---- GEMM3 partial: accO += Hs @ W2slice^T (4 chunks, no inner barriers) ----
        #pragma unroll
        for (int c = 0; c < 4; ++c) {
            short8 a3[4], b3[2];
            #pragma unroll
            for (int i = 0; i < 4; ++i) {
                const int tr = w0 * 64 + i * 16 + m16;           // token local
                const int ss = quad ^ ((tr >> 2) & 3);
                a3[i] = *reinterpret_cast<const short8*>(&Hs[c][tr * 32 + ss * 8]);
            }
            const u16* wsrc = ((c < 2) ? (const u16*)As : (const u16*)Bs) + (c & 1) * 2048;
            #pragma unroll
            for (int j = 0; j < 2; ++j) {
                const int rowb = w1 * 32 + j * 16 + m16;         // out col m
                const int ss = quad ^ ((rowb >> 2) & 3);
                b3[j] = *reinterpret_cast<const short8*>(wsrc + rowb * 32 + ss * 8);
            }
            #pragma unroll
            for (int i = 0; i < 4; ++i)
                #pragma unroll
                for (int j = 0; j < 2; ++j)
                    accO[i][j] = __builtin_amdgcn_mfma_f32_16x16x32_bf16(a3[i], b3[j], accO[i][j], 0, 0, 0);
        }
        __syncthreads();   // before next slice overwrites As/Bs/Hs
    }

    // ---- epilogue: out[r0+row][col] = accO + b2 ----
    #pragma unroll
    for (int j = 0; j < 2; ++j) {
        const int col = w1 * 32 + j * 16 + m16;
        const float bv = b2[col];
        #pragma unroll
        for (int i = 0; i < 4; ++i) {
            #pragma unroll
            for (int r = 0; r < 4; ++r) {
                const int row = w0 * 64 + i * 16 + quad * 4 + r;
                out[(r0 + row) * 64 + col] = accO[i][j][r] + bv;
            }
        }
    }
}

// ---------------- host ----------------

extern "C" void kernel_launch(void* const* d_in, const int* in_sizes, int n_in,
                              void* d_out, int out_size, void* d_ws, size_t ws_size,
                              hipStream_t stream) {
    const float* X      = (const float*)d_in[0];
    const float* Wq     = (const float*)d_in[1];
    const float* coeffs = (const float*)d_in[2];
    const float* W1     = (const float*)d_in[3];
    const float* b1     = (const float*)d_in[4];
    const float* W2     = (const float*)d_in[5];
    const float* b2     = (const float*)d_in[6];

    char* ws = (char*)d_ws;
    u16*   Xb  = (u16*)(ws);
    u16*   Wqb = (u16*)(ws + 12582912);
    u16*   W1b = (u16*)(ws + 13762560);
    u16*   W2b = (u16*)(ws + 14024704);
    float* b1e = (float*)(ws + 14090240);
    u16*   P   = (u16*)(ws + 14092288);

    // one fused prep launch (was 5 launches)
    prep<<<6882, 256, 0, stream>>>(X, Xb, Wq, Wqb, W1, W1b, W2, W2b, b1, coeffs, b1e);

    // GEMM1 + poly epilogue: P = poly(clip(Xb @ Wqb^T)), K folded 256->192
    gemm1_poly<<<dim3(128, 6), 256, 0, stream>>>(Xb, Wqb, coeffs, P);

    // fused GEMM2+GEMM3: out = relu(P @ W1[64:]^T + b1e) @ W2^T + b2
    gemm23<<<dim3(768), 256, 0, stream>>>(P, W1b, b1e, W2b, b2, (float*)d_out);
}